// Round 7
// baseline (453.025 us; speedup 1.0000x reference)
//
#include <hip/hip_runtime.h>
#include <math.h>

#define N_NODES 50000
#define E_EDGES 800000
#define D_DIM   128
#define H_HEADS 8
#define C_CH    16
#define HID_DIM 512
#define ED_DIM  32

typedef __attribute__((ext_vector_type(8))) short short8;
typedef __attribute__((ext_vector_type(4))) float f32x4;

__device__ __forceinline__ short f2bf(float f) {
    unsigned u = __float_as_uint(f);
    return (short)((u + 0x7FFFu + ((u >> 16) & 1u)) >> 16);  // RNE
}
__device__ __forceinline__ float bf2f(short s) {
    return __uint_as_float(((unsigned)(unsigned short)s) << 16);
}

// ============================================================
// Kernel R: repack w1/w2/Wl/Wr/We (fp32 [K][N]) into bf16
// B-fragment order for mfma_f32_16x16x32_bf16.
// We (Wep) additionally gets a COLUMN PERMUTATION: tile t, col m
// holds logical channel m*8+t, so the edge kernel's MFMA output
// lands directly in per-lane contiguous-channel layout (no LDS
// xe tile needed).
// ============================================================
__global__ __launch_bounds__(64) void repack_kernel(
    const float* __restrict__ w1, const float* __restrict__ w2,
    const float* __restrict__ Wl, const float* __restrict__ Wr,
    const float* __restrict__ We,
    short8* __restrict__ w1p, short8* __restrict__ w2p,
    short8* __restrict__ Wlp, short8* __restrict__ Wrp,
    short8* __restrict__ Wep)
{
    int b = blockIdx.x;
    const float* src; short8* dst; int Nw, nc, rel;
    bool perm = false;
    if (b < 128)      { src = w1; dst = w1p; Nw = 512; nc = 4;  rel = b; }
    else if (b < 256) { src = w2; dst = w2p; Nw = 128; nc = 16; rel = b - 128; }
    else if (b < 288) { src = Wl; dst = Wlp; Nw = 128; nc = 4;  rel = b - 256; }
    else if (b < 320) { src = Wr; dst = Wrp; Nw = 128; nc = 4;  rel = b - 288; }
    else              { src = We; dst = Wep; Nw = 128; nc = 1;  rel = b - 320; perm = true; }
    int t = rel / nc, c = rel % nc;
    int l = threadIdx.x, quad = l >> 4, col = l & 15;
    short8 r;
    #pragma unroll
    for (int j = 0; j < 8; ++j) {
        if (perm)
            r[j] = f2bf(src[(size_t)(quad * 8 + j) * 128 + col * 8 + t]);
        else
            r[j] = f2bf(src[(size_t)(c * 32 + quad * 8 + j) * Nw + t * 16 + col]);
    }
    dst[(size_t)rel * 64 + l] = r;
}

// ============================================================
// Kernel CNT: per-dst degree count + per-edge rank.
// ============================================================
__global__ __launch_bounds__(256) void count_kernel(
    const int* __restrict__ edge_index, unsigned* __restrict__ cnt,
    unsigned short* __restrict__ rank)
{
    int e = blockIdx.x * 256 + threadIdx.x;   // E % 256 == 0
    int dst = edge_index[E_EDGES + e];
    rank[e] = (unsigned short)atomicAdd(&cnt[dst], 1u);
}

// ============================================================
// Kernel A: MFMA node pipeline. 16 nodes/block, 256 thr (4 waves).
// ============================================================
__global__ __launch_bounds__(256) void node_ffn_mfma(
    const float* __restrict__ h,
    const float* __restrict__ b1, const float* __restrict__ b2,
    const float* __restrict__ ln_g, const float* __restrict__ ln_b,
    const float* __restrict__ bl, const float* __restrict__ br,
    const short8* __restrict__ w1p, const short8* __restrict__ w2p,
    const short8* __restrict__ Wlp, const short8* __restrict__ Wrp,
    float* __restrict__ v_out,
    unsigned short* __restrict__ xl_bf_out, unsigned short* __restrict__ xr_bf_out)
{
    __shared__ short hid_bf[16 * 520];
    __shared__ float v_s[16 * 132];
    __shared__ short v_bf[16 * 136];

    const int tid = threadIdx.x;
    const int w = tid >> 6, lane = tid & 63;
    const int m = lane & 15, quad = lane >> 4;
    const int n0 = blockIdx.x * 16;

    short8 af[4];
    #pragma unroll
    for (int c = 0; c < 4; ++c) {
        const float* hp = h + (size_t)(n0 + m) * 128 + c * 32 + quad * 8;
        float4 p0 = ((const float4*)hp)[0];
        float4 p1 = ((const float4*)hp)[1];
        short8 a;
        a[0] = f2bf(p0.x); a[1] = f2bf(p0.y); a[2] = f2bf(p0.z); a[3] = f2bf(p0.w);
        a[4] = f2bf(p1.x); a[5] = f2bf(p1.y); a[6] = f2bf(p1.z); a[7] = f2bf(p1.w);
        af[c] = a;
    }

    {
        f32x4 acc[8];
        #pragma unroll
        for (int t = 0; t < 8; ++t) acc[t] = (f32x4){0.f, 0.f, 0.f, 0.f};
        #pragma unroll
        for (int t = 0; t < 8; ++t) {
            int tile = w * 8 + t;
            #pragma unroll
            for (int c = 0; c < 4; ++c) {
                short8 bf = w1p[(size_t)(tile * 4 + c) * 64 + lane];
                acc[t] = __builtin_amdgcn_mfma_f32_16x16x32_bf16(af[c], bf, acc[t], 0, 0, 0);
            }
        }
        #pragma unroll
        for (int t = 0; t < 8; ++t) {
            int col = (w * 8 + t) * 16 + m;
            float bias = b1[col];
            #pragma unroll
            for (int r = 0; r < 4; ++r) {
                int row = quad * 4 + r;
                hid_bf[row * 520 + col] = f2bf(fmaxf(acc[t][r] + bias, 0.f));
            }
        }
    }
    __syncthreads();

    {
        f32x4 acc2[2];
        acc2[0] = (f32x4){0.f, 0.f, 0.f, 0.f};
        acc2[1] = (f32x4){0.f, 0.f, 0.f, 0.f};
        #pragma unroll 4
        for (int c = 0; c < 16; ++c) {
            short8 a = *(const short8*)&hid_bf[m * 520 + c * 32 + quad * 8];
            #pragma unroll
            for (int t = 0; t < 2; ++t) {
                short8 bf = w2p[(size_t)((w * 2 + t) * 16 + c) * 64 + lane];
                acc2[t] = __builtin_amdgcn_mfma_f32_16x16x32_bf16(a, bf, acc2[t], 0, 0, 0);
            }
        }
        #pragma unroll
        for (int t = 0; t < 2; ++t) {
            int col = (w * 2 + t) * 16 + m;
            float bias = b2[col];
            #pragma unroll
            for (int r = 0; r < 4; ++r) {
                int row = quad * 4 + r;
                v_s[row * 132 + col] = acc2[t][r] + bias + h[(size_t)(n0 + row) * 128 + col];
            }
        }
    }
    __syncthreads();

    {
        float g0 = ln_g[lane], g1 = ln_g[lane + 64];
        float be0 = ln_b[lane], be1 = ln_b[lane + 64];
        #pragma unroll
        for (int p = 0; p < 4; ++p) {
            int nd = w * 4 + p;
            float x0 = v_s[nd * 132 + lane], x1 = v_s[nd * 132 + lane + 64];
            float s = x0 + x1, ss = x0 * x0 + x1 * x1;
            #pragma unroll
            for (int off = 1; off < 64; off <<= 1) {
                s  += __shfl_xor(s, off);
                ss += __shfl_xor(ss, off);
            }
            float mu = s * (1.f / 128.f);
            float var = ss * (1.f / 128.f) - mu * mu;
            float rs = rsqrtf(var + 1e-5f);
            float y0 = (x0 - mu) * rs * g0 + be0;
            float y1 = (x1 - mu) * rs * g1 + be1;
            v_out[(size_t)(n0 + nd) * 128 + lane]      = y0;
            v_out[(size_t)(n0 + nd) * 128 + lane + 64] = y1;
            v_bf[nd * 136 + lane]      = f2bf(y0);
            v_bf[nd * 136 + lane + 64] = f2bf(y1);
        }
    }
    __syncthreads();

    {
        short8 af3[4];
        #pragma unroll
        for (int c = 0; c < 4; ++c)
            af3[c] = *(const short8*)&v_bf[m * 136 + c * 32 + quad * 8];
        f32x4 accl[2], accr[2];
        #pragma unroll
        for (int t = 0; t < 2; ++t) {
            accl[t] = (f32x4){0.f, 0.f, 0.f, 0.f};
            accr[t] = (f32x4){0.f, 0.f, 0.f, 0.f};
        }
        #pragma unroll
        for (int t = 0; t < 2; ++t) {
            int tile = w * 2 + t;
            #pragma unroll
            for (int c = 0; c < 4; ++c) {
                accl[t] = __builtin_amdgcn_mfma_f32_16x16x32_bf16(
                    af3[c], Wlp[(size_t)(tile * 4 + c) * 64 + lane], accl[t], 0, 0, 0);
                accr[t] = __builtin_amdgcn_mfma_f32_16x16x32_bf16(
                    af3[c], Wrp[(size_t)(tile * 4 + c) * 64 + lane], accr[t], 0, 0, 0);
            }
        }
        #pragma unroll
        for (int t = 0; t < 2; ++t) {
            int col = (w * 2 + t) * 16 + m;
            float bld = bl[col], brd = br[col];
            #pragma unroll
            for (int r = 0; r < 4; ++r) {
                int row = quad * 4 + r;
                xl_bf_out[(size_t)(n0 + row) * 128 + col] = (unsigned short)f2bf(accl[t][r] + bld);
                xr_bf_out[(size_t)(n0 + row) * 128 + col] = (unsigned short)f2bf(accr[t][r] + brd);
            }
        }
    }
}

// ============================================================
// Kernel S1: exclusive scan, single pass (R6 form).
// ============================================================
__global__ __launch_bounds__(1024) void scan_kernel(
    const unsigned* __restrict__ cnt, int* __restrict__ rowstart)
{
    __shared__ int wsum[16];
    const int t = threadIdx.x, wv = t >> 6, lane = t & 63;
    const int base4 = t * 13;
    int4 v[13];
    int lsum = 0;
    #pragma unroll
    for (int k = 0; k < 13; ++k) {
        int i4 = base4 + k;
        int4 x = make_int4(0, 0, 0, 0);
        if (i4 < N_NODES / 4) x = ((const int4*)cnt)[i4];
        v[k] = x;
        lsum += x.x + x.y + x.z + x.w;
    }
    int s = lsum;
    #pragma unroll
    for (int off = 1; off < 64; off <<= 1) {
        int nb = __shfl_up(s, off);
        if (lane >= off) s += nb;
    }
    if (lane == 63) wsum[wv] = s;
    __syncthreads();
    int woff = 0;
    for (int k = 0; k < wv; ++k) woff += wsum[k];
    int run = woff + s - lsum;          // exclusive prefix for this thread
    #pragma unroll
    for (int k = 0; k < 13; ++k) {
        int i4 = base4 + k;
        if (i4 < N_NODES / 4) {
            int4 r;
            r.x = run; run += v[k].x;
            r.y = run; run += v[k].y;
            r.z = run; run += v[k].z;
            r.w = run; run += v[k].w;
            ((int4*)rowstart)[i4] = r;
        }
    }
}

// ============================================================
// Kernel S2: scatter edge ids + packed (src,dst) into CSR order
// ============================================================
__global__ __launch_bounds__(256) void scatter_kernel(
    const int* __restrict__ edge_index, const unsigned short* __restrict__ rank,
    const int* __restrict__ rowstart, int* __restrict__ eidx,
    unsigned* __restrict__ srcdst)
{
    int e = blockIdx.x * 256 + threadIdx.x;
    if (e >= E_EDGES) return;
    int src = edge_index[e];
    int dst = edge_index[E_EDGES + e];
    int pos = rowstart[dst] + (int)rank[e];
    eidx[pos] = e;
    srcdst[pos] = (unsigned)src | ((unsigned)dst << 16);   // N < 65536
}

// ============================================================
// Kernel B: edge ex, CSR order. xe stays ENTIRELY in registers:
// Wep's column permutation makes MFMA output acc[t][r] = channels
// m*8+t of edge quad*4+r — the exact consumption layout. No xe
// LDS tile, no bf16 round-trip, LDS = We staging only (8.2 KB ->
// occupancy cap 100%). leaky = max(x, 0.2x); fast __expf.
// ============================================================
__global__ __launch_bounds__(256) void edge_logits_mfma(
    const int* __restrict__ eidx, const unsigned* __restrict__ srcdst,
    const float* __restrict__ edge_attr,
    const short8* __restrict__ Wep, const float* __restrict__ att,
    const unsigned short* __restrict__ xl_bf, const unsigned short* __restrict__ xr_bf,
    float* __restrict__ exbuf)
{
    __shared__ short8 We_f[512];       // 8 KB, permuted B-frag order
    const int tid = threadIdx.x;
    const int w = tid >> 6, lane = tid & 63;
    const int m = lane & 15, quad = lane >> 4;
    const int p0b = blockIdx.x * 64;   // CSR position base

    We_f[tid]       = Wep[tid];
    We_f[tid + 256] = Wep[tid + 256];

    // A-frag: lane (quad,m) loads ea row of edge (w*16+m), k = quad*8..+7
    int em = eidx[p0b + w * 16 + m];
    const float* eap = edge_attr + (size_t)em * 32 + quad * 8;
    float4 p0 = ((const float4*)eap)[0];
    float4 p1 = ((const float4*)eap)[1];
    short8 a;
    a[0] = f2bf(p0.x); a[1] = f2bf(p0.y); a[2] = f2bf(p0.z); a[3] = f2bf(p0.w);
    a[4] = f2bf(p1.x); a[5] = f2bf(p1.y); a[6] = f2bf(p1.z); a[7] = f2bf(p1.w);

    __syncthreads();   // We_f ready (only barrier in kernel)

    // xe = ea @ We_perm : lane holds edge (w*16 + quad*4 + r),
    // channels m*8+t in acc[t][r] (f32, never leaves registers)
    f32x4 acc[8];
    #pragma unroll
    for (int t = 0; t < 8; ++t) acc[t] = (f32x4){0.f, 0.f, 0.f, 0.f};
    #pragma unroll
    for (int t = 0; t < 8; ++t)
        acc[t] = __builtin_amdgcn_mfma_f32_16x16x32_bf16(a, We_f[t * 64 + lane], acc[t], 0, 0, 0);

    const int d0 = m * 8;
    float4 at0 = ((const float4*)(att + d0))[0];
    float4 at1 = ((const float4*)(att + d0))[1];
    float atv[8] = { at0.x, at0.y, at0.z, at0.w, at1.x, at1.y, at1.z, at1.w };

    // per-edge phase: lane's 4 edges (r), channels d0..d0+7
    #pragma unroll
    for (int r = 0; r < 4; ++r) {
        int el = w * 16 + quad * 4 + r;
        unsigned sd = srcdst[p0b + el];          // broadcast per 16 lanes
        int src = (int)(sd & 0xffffu);
        int dst = (int)(sd >> 16);
        short8 xl8 = *(const short8*)&xl_bf[(size_t)src * 128 + d0];
        short8 xr8 = *(const short8*)&xr_bf[(size_t)dst * 128 + d0];

        float pq = 0.f;
        #pragma unroll
        for (int t = 0; t < 8; ++t) {
            float x = bf2f(xl8[t]) + bf2f(xr8[t]) + acc[t][r];
            x = fmaxf(x, 0.2f * x);              // leakyrelu(x, 0.2), slope<1
            pq += x * atv[t];
        }
        pq += __shfl_xor(pq, 1);                 // lanes 2h,2h+1 hold logit[h]
        if ((m & 1) == 0)
            exbuf[(size_t)(p0b + el) * 8 + (m >> 1)] = __expf(pq);
    }
}

// ============================================================
// Kernel C: per-node aggregation, ONE pass with 8 edges in
// flight: U = sum ex*xl, den = sum ex; out = LN(U/den+bias+v);
// alpha sweep writes alpha[e][h] = ex*inv.
// ============================================================
__global__ __launch_bounds__(256) void node_aggregate_kernel(
    const int* __restrict__ eidx, const int* __restrict__ rowstart,
    const unsigned* __restrict__ cnt, const unsigned* __restrict__ srcdst,
    const float* __restrict__ exbuf,
    const unsigned short* __restrict__ xl_bf, const float* __restrict__ v,
    const float* __restrict__ bias_out,
    const float* __restrict__ ln_g, const float* __restrict__ ln_b,
    float* __restrict__ alpha_out, float* __restrict__ out)
{
    const int wv = threadIdx.x >> 6, lane = threadIdx.x & 63;
    const int n = blockIdx.x * 4 + wv;
    if (n >= N_NODES) return;
    const int start = rowstart[n];
    const int num = (int)cnt[n];

    const int g = lane >> 4, s = lane & 15;
    const int h3 = s >> 1;
    float acc[8] = {0.f, 0.f, 0.f, 0.f, 0.f, 0.f, 0.f, 0.f};
    float den = 0.f;

    int i = 0;
    for (; i + 8 <= num; i += 8) {
        int pos0 = start + i + g;
        int pos1 = pos0 + 4;
        unsigned sda = srcdst[pos0];
        unsigned sdb = srcdst[pos1];
        float exa = exbuf[(size_t)pos0 * 8 + h3];
        float exb = exbuf[(size_t)pos1 * 8 + h3];
        short8 qa = *(const short8*)&xl_bf[(size_t)(sda & 0xffffu) * 128 + s * 8];
        short8 qb = *(const short8*)&xl_bf[(size_t)(sdb & 0xffffu) * 128 + s * 8];
        if ((s & 1) == 0) den += exa + exb;
        #pragma unroll
        for (int k = 0; k < 8; ++k) {
            acc[k] += bf2f(qa[k]) * exa;
            acc[k] += bf2f(qb[k]) * exb;
        }
    }
    for (; i < num; i += 4) {
        int ii = i + g;
        if (ii < num) {
            int pos = start + ii;
            int src = (int)(srcdst[pos] & 0xffffu);
            float ex = exbuf[(size_t)pos * 8 + h3];
            if ((s & 1) == 0) den += ex;
            short8 q = *(const short8*)&xl_bf[(size_t)src * 128 + s * 8];
            #pragma unroll
            for (int k = 0; k < 8; ++k) acc[k] += bf2f(q[k]) * ex;
        }
    }
    #pragma unroll
    for (int k = 0; k < 8; ++k) {
        acc[k] += __shfl_xor(acc[k], 16);
        acc[k] += __shfl_xor(acc[k], 32);
    }
    den += __shfl_xor(den, 16);
    den += __shfl_xor(den, 32);
    float den_h = __shfl(den, 2 * h3);
    float inv = (num > 0) ? (1.f / den_h) : 0.f;

    const float* vp = v + (size_t)n * 128 + s * 8;
    float4 v0 = ((const float4*)vp)[0], v1 = ((const float4*)vp)[1];
    float4 b0 = ((const float4*)(bias_out + s * 8))[0];
    float4 b1 = ((const float4*)(bias_out + s * 8))[1];
    float x[8];
    x[0] = acc[0] * inv + b0.x + v0.x; x[1] = acc[1] * inv + b0.y + v0.y;
    x[2] = acc[2] * inv + b0.z + v0.z; x[3] = acc[3] * inv + b0.w + v0.w;
    x[4] = acc[4] * inv + b1.x + v1.x; x[5] = acc[5] * inv + b1.y + v1.y;
    x[6] = acc[6] * inv + b1.z + v1.z; x[7] = acc[7] * inv + b1.w + v1.w;
    float sm = 0.f, ssm = 0.f;
    #pragma unroll
    for (int k = 0; k < 8; ++k) { sm += x[k]; ssm += x[k] * x[k]; }
    #pragma unroll
    for (int off = 1; off < 16; off <<= 1) {
        sm  += __shfl_xor(sm, off);
        ssm += __shfl_xor(ssm, off);
    }
    float mu = sm * (1.f / 128.f);
    float var = ssm * (1.f / 128.f) - mu * mu;
    float rs = rsqrtf(var + 1e-5f);
    if (g == 0) {
        float4 g0 = ((const float4*)(ln_g + s * 8))[0];
        float4 g1 = ((const float4*)(ln_g + s * 8))[1];
        float4 be0 = ((const float4*)(ln_b + s * 8))[0];
        float4 be1 = ((const float4*)(ln_b + s * 8))[1];
        float4 o0, o1;
        o0.x = (x[0] - mu) * rs * g0.x + be0.x;
        o0.y = (x[1] - mu) * rs * g0.y + be0.y;
        o0.z = (x[2] - mu) * rs * g0.z + be0.z;
        o0.w = (x[3] - mu) * rs * g0.w + be0.w;
        o1.x = (x[4] - mu) * rs * g1.x + be1.x;
        o1.y = (x[5] - mu) * rs * g1.y + be1.y;
        o1.z = (x[6] - mu) * rs * g1.z + be1.z;
        o1.w = (x[7] - mu) * rs * g1.w + be1.w;
        float4* op = (float4*)(out + (size_t)n * 128 + s * 8);
        op[0] = o0; op[1] = o1;
    }

    if (num > 0) {
        const int h7 = lane & 7, j8 = lane >> 3;
        float invh = __shfl(inv, 2 * h7);
        for (int i2 = j8; i2 < num; i2 += 8) {
            int pos = start + i2;
            float ex = exbuf[(size_t)pos * 8 + h7];
            int e = eidx[pos];
            alpha_out[(size_t)e * 8 + h7] = ex * invh;
        }
    }
}

// ============================================================
extern "C" void kernel_launch(void* const* d_in, const int* in_sizes, int n_in,
                              void* d_out, int out_size, void* d_ws, size_t ws_size,
                              hipStream_t stream)
{
    const float* h        = (const float*)d_in[0];
    const int*   edge_idx = (const int*)  d_in[1];
    const float* edge_attr= (const float*)d_in[2];
    const float* w1       = (const float*)d_in[3];
    const float* b1       = (const float*)d_in[4];
    const float* w2       = (const float*)d_in[5];
    const float* b2       = (const float*)d_in[6];
    const float* ln_g     = (const float*)d_in[7];
    const float* ln_b     = (const float*)d_in[8];
    const float* Wl       = (const float*)d_in[9];
    const float* bl       = (const float*)d_in[10];
    const float* Wr       = (const float*)d_in[11];
    const float* br       = (const float*)d_in[12];
    const float* We       = (const float*)d_in[13];
    const float* att      = (const float*)d_in[14];
    const float* bias_out = (const float*)d_in[15];

    float* out   = (float*)d_out;                       // [N,128]
    float* alpha = out + (size_t)N_NODES * 128;         // [E,8] final alpha

    short8* w1p = (short8*)alpha;                       // packed weights live in
    short8* w2p = w1p + 128 * 64;                       // alpha region, consumed by
    short8* Wlp = w2p + 128 * 64;                       // node_ffn; alpha written last
    short8* Wrp = Wlp + 32 * 64;

    float*          v        = (float*)d_ws;                               // [N,128] f32
    unsigned short* xl_bf    = (unsigned short*)(v + (size_t)N_NODES*128); // [N,128] bf16
    unsigned short* xr_bf    = xl_bf + (size_t)N_NODES * 128;              // [N,128] bf16
    float*          exbuf    = (float*)(xr_bf + (size_t)N_NODES * 128);    // [E,8] f32 (ex)
    unsigned*       cnt      = (unsigned*)(exbuf + (size_t)E_EDGES * 8);   // [N]
    int*            rowstart = (int*)(cnt + N_NODES);                      // [N]
    unsigned short* rank     = (unsigned short*)(rowstart + N_NODES);      // [E]
    short8*         Wep      = (short8*)(rank + E_EDGES);                  // [512] 8 KB
    int*            eidx     = (int*)(Wep + 512);                          // [E]
    unsigned*       srcdst   = (unsigned*)(eidx + E_EDGES);                // [E]

    hipMemsetAsync(cnt, 0, (size_t)N_NODES * sizeof(unsigned), stream);

    repack_kernel<<<328, 64, 0, stream>>>(w1, w2, Wl, Wr, We,
                                          w1p, w2p, Wlp, Wrp, Wep);
    count_kernel<<<E_EDGES / 256, 256, 0, stream>>>(edge_idx, cnt, rank);
    node_ffn_mfma<<<N_NODES / 16, 256, 0, stream>>>(
        h, b1, b2, ln_g, ln_b, bl, br, w1p, w2p, Wlp, Wrp, v, xl_bf, xr_bf);
    scan_kernel<<<1, 1024, 0, stream>>>(cnt, rowstart);
    scatter_kernel<<<(E_EDGES + 255) / 256, 256, 0, stream>>>(
        edge_idx, rank, rowstart, eidx, srcdst);
    edge_logits_mfma<<<E_EDGES / 64, 256, 0, stream>>>(
        eidx, srcdst, edge_attr, Wep, att, xl_bf, xr_bf, exbuf);
    node_aggregate_kernel<<<(N_NODES + 3) / 4, 256, 0, stream>>>(
        eidx, rowstart, cnt, srcdst, exbuf, xl_bf, v, bias_out, ln_g, ln_b, alpha, out);
}

// Round 9
// 440.520 us; speedup vs baseline: 1.0284x; 1.0284x over previous
//
#include <hip/hip_runtime.h>
#include <math.h>

#define N_NODES 50000
#define E_EDGES 800000
#define D_DIM   128
#define H_HEADS 8
#define C_CH    16
#define HID_DIM 512
#define ED_DIM  32

typedef __attribute__((ext_vector_type(8))) short short8;
typedef __attribute__((ext_vector_type(4))) float f32x4;

__device__ __forceinline__ short f2bf(float f) {
    unsigned u = __float_as_uint(f);
    return (short)((u + 0x7FFFu + ((u >> 16) & 1u)) >> 16);  // RNE
}
__device__ __forceinline__ float bf2f(short s) {
    return __uint_as_float(((unsigned)(unsigned short)s) << 16);
}

// ============================================================
// Kernel R: repack w1/w2/Wl/Wr/We (fp32 [K][N]) into bf16
// B-fragment order for mfma_f32_16x16x32_bf16.
// We (Wep) gets a COLUMN PERMUTATION: tile t, col m holds logical
// channel m*8+t, so the edge kernel's MFMA output lands directly
// in per-lane contiguous-channel layout (register-resident xe).
// ============================================================
__global__ __launch_bounds__(64) void repack_kernel(
    const float* __restrict__ w1, const float* __restrict__ w2,
    const float* __restrict__ Wl, const float* __restrict__ Wr,
    const float* __restrict__ We,
    short8* __restrict__ w1p, short8* __restrict__ w2p,
    short8* __restrict__ Wlp, short8* __restrict__ Wrp,
    short8* __restrict__ Wep)
{
    int b = blockIdx.x;
    const float* src; short8* dst; int Nw, nc, rel;
    bool perm = false;
    if (b < 128)      { src = w1; dst = w1p; Nw = 512; nc = 4;  rel = b; }
    else if (b < 256) { src = w2; dst = w2p; Nw = 128; nc = 16; rel = b - 128; }
    else if (b < 288) { src = Wl; dst = Wlp; Nw = 128; nc = 4;  rel = b - 256; }
    else if (b < 320) { src = Wr; dst = Wrp; Nw = 128; nc = 4;  rel = b - 288; }
    else              { src = We; dst = Wep; Nw = 128; nc = 1;  rel = b - 320; perm = true; }
    int t = rel / nc, c = rel % nc;
    int l = threadIdx.x, quad = l >> 4, col = l & 15;
    short8 r;
    #pragma unroll
    for (int j = 0; j < 8; ++j) {
        if (perm)
            r[j] = f2bf(src[(size_t)(quad * 8 + j) * 128 + col * 8 + t]);
        else
            r[j] = f2bf(src[(size_t)(c * 32 + quad * 8 + j) * Nw + t * 16 + col]);
    }
    dst[(size_t)rel * 64 + l] = r;
}

// ============================================================
// Kernel CNT: per-dst degree count + per-edge rank.
// ============================================================
__global__ __launch_bounds__(256) void count_kernel(
    const int* __restrict__ edge_index, unsigned* __restrict__ cnt,
    unsigned short* __restrict__ rank)
{
    int e = blockIdx.x * 256 + threadIdx.x;   // E % 256 == 0
    int dst = edge_index[E_EDGES + e];
    rank[e] = (unsigned short)atomicAdd(&cnt[dst], 1u);
}

// ============================================================
// Kernel A: MFMA node pipeline. 16 nodes/block, 256 thr (4 waves).
// ============================================================
__global__ __launch_bounds__(256) void node_ffn_mfma(
    const float* __restrict__ h,
    const float* __restrict__ b1, const float* __restrict__ b2,
    const float* __restrict__ ln_g, const float* __restrict__ ln_b,
    const float* __restrict__ bl, const float* __restrict__ br,
    const short8* __restrict__ w1p, const short8* __restrict__ w2p,
    const short8* __restrict__ Wlp, const short8* __restrict__ Wrp,
    float* __restrict__ v_out,
    unsigned short* __restrict__ xl_bf_out, unsigned short* __restrict__ xr_bf_out)
{
    __shared__ short hid_bf[16 * 520];
    __shared__ float v_s[16 * 132];
    __shared__ short v_bf[16 * 136];

    const int tid = threadIdx.x;
    const int w = tid >> 6, lane = tid & 63;
    const int m = lane & 15, quad = lane >> 4;
    const int n0 = blockIdx.x * 16;

    short8 af[4];
    #pragma unroll
    for (int c = 0; c < 4; ++c) {
        const float* hp = h + (size_t)(n0 + m) * 128 + c * 32 + quad * 8;
        float4 p0 = ((const float4*)hp)[0];
        float4 p1 = ((const float4*)hp)[1];
        short8 a;
        a[0] = f2bf(p0.x); a[1] = f2bf(p0.y); a[2] = f2bf(p0.z); a[3] = f2bf(p0.w);
        a[4] = f2bf(p1.x); a[5] = f2bf(p1.y); a[6] = f2bf(p1.z); a[7] = f2bf(p1.w);
        af[c] = a;
    }

    {
        f32x4 acc[8];
        #pragma unroll
        for (int t = 0; t < 8; ++t) acc[t] = (f32x4){0.f, 0.f, 0.f, 0.f};
        #pragma unroll
        for (int t = 0; t < 8; ++t) {
            int tile = w * 8 + t;
            #pragma unroll
            for (int c = 0; c < 4; ++c) {
                short8 bf = w1p[(size_t)(tile * 4 + c) * 64 + lane];
                acc[t] = __builtin_amdgcn_mfma_f32_16x16x32_bf16(af[c], bf, acc[t], 0, 0, 0);
            }
        }
        #pragma unroll
        for (int t = 0; t < 8; ++t) {
            int col = (w * 8 + t) * 16 + m;
            float bias = b1[col];
            #pragma unroll
            for (int r = 0; r < 4; ++r) {
                int row = quad * 4 + r;
                hid_bf[row * 520 + col] = f2bf(fmaxf(acc[t][r] + bias, 0.f));
            }
        }
    }
    __syncthreads();

    {
        f32x4 acc2[2];
        acc2[0] = (f32x4){0.f, 0.f, 0.f, 0.f};
        acc2[1] = (f32x4){0.f, 0.f, 0.f, 0.f};
        #pragma unroll 4
        for (int c = 0; c < 16; ++c) {
            short8 a = *(const short8*)&hid_bf[m * 520 + c * 32 + quad * 8];
            #pragma unroll
            for (int t = 0; t < 2; ++t) {
                short8 bf = w2p[(size_t)((w * 2 + t) * 16 + c) * 64 + lane];
                acc2[t] = __builtin_amdgcn_mfma_f32_16x16x32_bf16(a, bf, acc2[t], 0, 0, 0);
            }
        }
        #pragma unroll
        for (int t = 0; t < 2; ++t) {
            int col = (w * 2 + t) * 16 + m;
            float bias = b2[col];
            #pragma unroll
            for (int r = 0; r < 4; ++r) {
                int row = quad * 4 + r;
                v_s[row * 132 + col] = acc2[t][r] + bias + h[(size_t)(n0 + row) * 128 + col];
            }
        }
    }
    __syncthreads();

    {
        float g0 = ln_g[lane], g1 = ln_g[lane + 64];
        float be0 = ln_b[lane], be1 = ln_b[lane + 64];
        #pragma unroll
        for (int p = 0; p < 4; ++p) {
            int nd = w * 4 + p;
            float x0 = v_s[nd * 132 + lane], x1 = v_s[nd * 132 + lane + 64];
            float s = x0 + x1, ss = x0 * x0 + x1 * x1;
            #pragma unroll
            for (int off = 1; off < 64; off <<= 1) {
                s  += __shfl_xor(s, off);
                ss += __shfl_xor(ss, off);
            }
            float mu = s * (1.f / 128.f);
            float var = ss * (1.f / 128.f) - mu * mu;
            float rs = rsqrtf(var + 1e-5f);
            float y0 = (x0 - mu) * rs * g0 + be0;
            float y1 = (x1 - mu) * rs * g1 + be1;
            v_out[(size_t)(n0 + nd) * 128 + lane]      = y0;
            v_out[(size_t)(n0 + nd) * 128 + lane + 64] = y1;
            v_bf[nd * 136 + lane]      = f2bf(y0);
            v_bf[nd * 136 + lane + 64] = f2bf(y1);
        }
    }
    __syncthreads();

    {
        short8 af3[4];
        #pragma unroll
        for (int c = 0; c < 4; ++c)
            af3[c] = *(const short8*)&v_bf[m * 136 + c * 32 + quad * 8];
        f32x4 accl[2], accr[2];
        #pragma unroll
        for (int t = 0; t < 2; ++t) {
            accl[t] = (f32x4){0.f, 0.f, 0.f, 0.f};
            accr[t] = (f32x4){0.f, 0.f, 0.f, 0.f};
        }
        #pragma unroll
        for (int t = 0; t < 2; ++t) {
            int tile = w * 2 + t;
            #pragma unroll
            for (int c = 0; c < 4; ++c) {
                accl[t] = __builtin_amdgcn_mfma_f32_16x16x32_bf16(
                    af3[c], Wlp[(size_t)(tile * 4 + c) * 64 + lane], accl[t], 0, 0, 0);
                accr[t] = __builtin_amdgcn_mfma_f32_16x16x32_bf16(
                    af3[c], Wrp[(size_t)(tile * 4 + c) * 64 + lane], accr[t], 0, 0, 0);
            }
        }
        #pragma unroll
        for (int t = 0; t < 2; ++t) {
            int col = (w * 2 + t) * 16 + m;
            float bld = bl[col], brd = br[col];
            #pragma unroll
            for (int r = 0; r < 4; ++r) {
                int row = quad * 4 + r;
                xl_bf_out[(size_t)(n0 + row) * 128 + col] = (unsigned short)f2bf(accl[t][r] + bld);
                xr_bf_out[(size_t)(n0 + row) * 128 + col] = (unsigned short)f2bf(accr[t][r] + brd);
            }
        }
    }
}

// ============================================================
// Kernel S1: exclusive scan, single pass (R6 form).
// ============================================================
__global__ __launch_bounds__(1024) void scan_kernel(
    const unsigned* __restrict__ cnt, int* __restrict__ rowstart)
{
    __shared__ int wsum[16];
    const int t = threadIdx.x, wv = t >> 6, lane = t & 63;
    const int base4 = t * 13;
    int4 v[13];
    int lsum = 0;
    #pragma unroll
    for (int k = 0; k < 13; ++k) {
        int i4 = base4 + k;
        int4 x = make_int4(0, 0, 0, 0);
        if (i4 < N_NODES / 4) x = ((const int4*)cnt)[i4];
        v[k] = x;
        lsum += x.x + x.y + x.z + x.w;
    }
    int s = lsum;
    #pragma unroll
    for (int off = 1; off < 64; off <<= 1) {
        int nb = __shfl_up(s, off);
        if (lane >= off) s += nb;
    }
    if (lane == 63) wsum[wv] = s;
    __syncthreads();
    int woff = 0;
    for (int k = 0; k < wv; ++k) woff += wsum[k];
    int run = woff + s - lsum;          // exclusive prefix for this thread
    #pragma unroll
    for (int k = 0; k < 13; ++k) {
        int i4 = base4 + k;
        if (i4 < N_NODES / 4) {
            int4 r;
            r.x = run; run += v[k].x;
            r.y = run; run += v[k].y;
            r.z = run; run += v[k].z;
            r.w = run; run += v[k].w;
            ((int4*)rowstart)[i4] = r;
        }
    }
}

// ============================================================
// Kernel S2: scatter edge ids + packed (src,dst) into CSR order
// ============================================================
__global__ __launch_bounds__(256) void scatter_kernel(
    const int* __restrict__ edge_index, const unsigned short* __restrict__ rank,
    const int* __restrict__ rowstart, int* __restrict__ eidx,
    unsigned* __restrict__ srcdst)
{
    int e = blockIdx.x * 256 + threadIdx.x;
    if (e >= E_EDGES) return;
    int src = edge_index[e];
    int dst = edge_index[E_EDGES + e];
    int pos = rowstart[dst] + (int)rank[e];
    eidx[pos] = e;
    srcdst[pos] = (unsigned)src | ((unsigned)dst << 16);   // N < 65536
}

// ============================================================
// Kernel B: edge ex, CSR order. Register-resident xe (permuted
// Wep) + REGISTER-prefetched CSR meta: each lane's 4 srcdst
// entries are one aligned uint4, loaded pre-barrier so the
// per-edge phase has no dependent global chain heads (R7's
// regression). LDS = We staging only (8 KB); one barrier.
// ============================================================
__global__ __launch_bounds__(256) void edge_logits_mfma(
    const int* __restrict__ eidx, const unsigned* __restrict__ srcdst,
    const float* __restrict__ edge_attr,
    const short8* __restrict__ Wep, const float* __restrict__ att,
    const unsigned short* __restrict__ xl_bf, const unsigned short* __restrict__ xr_bf,
    float* __restrict__ exbuf)
{
    __shared__ short8 We_f[512];       // 8 KB, permuted B-frag order
    const int tid = threadIdx.x;
    const int w = tid >> 6, lane = tid & 63;
    const int m = lane & 15, quad = lane >> 4;
    const int p0b = blockIdx.x * 64;   // CSR position base

    We_f[tid]       = Wep[tid];
    We_f[tid + 256] = Wep[tid + 256];

    // register prefetch: this lane's 4 edges' (src,dst), one aligned 16B load
    // (broadcast within each 16-lane group; issued before the barrier so it
    // overlaps We staging + the edge_attr gather + the MFMA chain)
    uint4 sd4 = *((const uint4*)&srcdst[p0b + w * 16 + quad * 4]);

    // A-frag: lane (quad,m) loads ea row of edge (w*16+m), k = quad*8..+7
    int em = eidx[p0b + w * 16 + m];
    const float* eap = edge_attr + (size_t)em * 32 + quad * 8;
    float4 p0 = ((const float4*)eap)[0];
    float4 p1 = ((const float4*)eap)[1];
    short8 a;
    a[0] = f2bf(p0.x); a[1] = f2bf(p0.y); a[2] = f2bf(p0.z); a[3] = f2bf(p0.w);
    a[4] = f2bf(p1.x); a[5] = f2bf(p1.y); a[6] = f2bf(p1.z); a[7] = f2bf(p1.w);

    __syncthreads();   // We_f ready (only barrier in kernel)

    // xe = ea @ We_perm : lane holds edge (w*16 + quad*4 + r),
    // channels m*8+t in acc[t][r] (f32, never leaves registers)
    f32x4 acc[8];
    #pragma unroll
    for (int t = 0; t < 8; ++t) acc[t] = (f32x4){0.f, 0.f, 0.f, 0.f};
    #pragma unroll
    for (int t = 0; t < 8; ++t)
        acc[t] = __builtin_amdgcn_mfma_f32_16x16x32_bf16(a, We_f[t * 64 + lane], acc[t], 0, 0, 0);

    const int d0 = m * 8;
    float4 at0 = ((const float4*)(att + d0))[0];
    float4 at1 = ((const float4*)(att + d0))[1];
    float atv[8] = { at0.x, at0.y, at0.z, at0.w, at1.x, at1.y, at1.z, at1.w };
    const unsigned sds[4] = { sd4.x, sd4.y, sd4.z, sd4.w };

    // per-edge phase: lane's 4 edges (r), channels d0..d0+7;
    // all addresses ready from registers -> 8 gathers in flight
    #pragma unroll
    for (int r = 0; r < 4; ++r) {
        int el = w * 16 + quad * 4 + r;
        unsigned sd = sds[r];
        int src = (int)(sd & 0xffffu);
        int dst = (int)(sd >> 16);
        short8 xl8 = *(const short8*)&xl_bf[(size_t)src * 128 + d0];
        short8 xr8 = *(const short8*)&xr_bf[(size_t)dst * 128 + d0];

        float pq = 0.f;
        #pragma unroll
        for (int t = 0; t < 8; ++t) {
            float x = bf2f(xl8[t]) + bf2f(xr8[t]) + acc[t][r];
            x = fmaxf(x, 0.2f * x);              // leakyrelu(x, 0.2)
            pq += x * atv[t];
        }
        pq += __shfl_xor(pq, 1);                 // lanes 2h,2h+1 hold logit[h]
        if ((m & 1) == 0)
            exbuf[(size_t)(p0b + el) * 8 + (m >> 1)] = __expf(pq);
    }
}

// ============================================================
// Kernel C: per-node aggregation, ONE pass with 8 edges in
// flight: U = sum ex*xl, den = sum ex; out = LN(U/den+bias+v);
// alpha sweep writes alpha[e][h] = ex*inv.
// ============================================================
__global__ __launch_bounds__(256) void node_aggregate_kernel(
    const int* __restrict__ eidx, const int* __restrict__ rowstart,
    const unsigned* __restrict__ cnt, const unsigned* __restrict__ srcdst,
    const float* __restrict__ exbuf,
    const unsigned short* __restrict__ xl_bf, const float* __restrict__ v,
    const float* __restrict__ bias_out,
    const float* __restrict__ ln_g, const float* __restrict__ ln_b,
    float* __restrict__ alpha_out, float* __restrict__ out)
{
    const int wv = threadIdx.x >> 6, lane = threadIdx.x & 63;
    const int n = blockIdx.x * 4 + wv;
    if (n >= N_NODES) return;
    const int start = rowstart[n];
    const int num = (int)cnt[n];

    const int g = lane >> 4, s = lane & 15;
    const int h3 = s >> 1;
    float acc[8] = {0.f, 0.f, 0.f, 0.f, 0.f, 0.f, 0.f, 0.f};
    float den = 0.f;

    int i = 0;
    for (; i + 8 <= num; i += 8) {
        int pos0 = start + i + g;
        int pos1 = pos0 + 4;
        unsigned sda = srcdst[pos0];
        unsigned sdb = srcdst[pos1];
        float exa = exbuf[(size_t)pos0 * 8 + h3];
        float exb = exbuf[(size_t)pos1 * 8 + h3];
        short8 qa = *(const short8*)&xl_bf[(size_t)(sda & 0xffffu) * 128 + s * 8];
        short8 qb = *(const short8*)&xl_bf[(size_t)(sdb & 0xffffu) * 128 + s * 8];
        if ((s & 1) == 0) den += exa + exb;
        #pragma unroll
        for (int k = 0; k < 8; ++k) {
            acc[k] += bf2f(qa[k]) * exa;
            acc[k] += bf2f(qb[k]) * exb;
        }
    }
    for (; i < num; i += 4) {
        int ii = i + g;
        if (ii < num) {
            int pos = start + ii;
            int src = (int)(srcdst[pos] & 0xffffu);
            float ex = exbuf[(size_t)pos * 8 + h3];
            if ((s & 1) == 0) den += ex;
            short8 q = *(const short8*)&xl_bf[(size_t)src * 128 + s * 8];
            #pragma unroll
            for (int k = 0; k < 8; ++k) acc[k] += bf2f(q[k]) * ex;
        }
    }
    #pragma unroll
    for (int k = 0; k < 8; ++k) {
        acc[k] += __shfl_xor(acc[k], 16);
        acc[k] += __shfl_xor(acc[k], 32);
    }
    den += __shfl_xor(den, 16);
    den += __shfl_xor(den, 32);
    float den_h = __shfl(den, 2 * h3);
    float inv = (num > 0) ? (1.f / den_h) : 0.f;

    const float* vp = v + (size_t)n * 128 + s * 8;
    float4 v0 = ((const float4*)vp)[0], v1 = ((const float4*)vp)[1];
    float4 b0 = ((const float4*)(bias_out + s * 8))[0];
    float4 b1 = ((const float4*)(bias_out + s * 8))[1];
    float x[8];
    x[0] = acc[0] * inv + b0.x + v0.x; x[1] = acc[1] * inv + b0.y + v0.y;
    x[2] = acc[2] * inv + b0.z + v0.z; x[3] = acc[3] * inv + b0.w + v0.w;
    x[4] = acc[4] * inv + b1.x + v1.x; x[5] = acc[5] * inv + b1.y + v1.y;
    x[6] = acc[6] * inv + b1.z + v1.z; x[7] = acc[7] * inv + b1.w + v1.w;
    float sm = 0.f, ssm = 0.f;
    #pragma unroll
    for (int k = 0; k < 8; ++k) { sm += x[k]; ssm += x[k] * x[k]; }
    #pragma unroll
    for (int off = 1; off < 16; off <<= 1) {
        sm  += __shfl_xor(sm, off);
        ssm += __shfl_xor(ssm, off);
    }
    float mu = sm * (1.f / 128.f);
    float var = ssm * (1.f / 128.f) - mu * mu;
    float rs = rsqrtf(var + 1e-5f);
    if (g == 0) {
        float4 g0 = ((const float4*)(ln_g + s * 8))[0];
        float4 g1 = ((const float4*)(ln_g + s * 8))[1];
        float4 be0 = ((const float4*)(ln_b + s * 8))[0];
        float4 be1 = ((const float4*)(ln_b + s * 8))[1];
        float4 o0, o1;
        o0.x = (x[0] - mu) * rs * g0.x + be0.x;
        o0.y = (x[1] - mu) * rs * g0.y + be0.y;
        o0.z = (x[2] - mu) * rs * g0.z + be0.z;
        o0.w = (x[3] - mu) * rs * g0.w + be0.w;
        o1.x = (x[4] - mu) * rs * g1.x + be1.x;
        o1.y = (x[5] - mu) * rs * g1.y + be1.y;
        o1.z = (x[6] - mu) * rs * g1.z + be1.z;
        o1.w = (x[7] - mu) * rs * g1.w + be1.w;
        float4* op = (float4*)(out + (size_t)n * 128 + s * 8);
        op[0] = o0; op[1] = o1;
    }

    if (num > 0) {
        const int h7 = lane & 7, j8 = lane >> 3;
        float invh = __shfl(inv, 2 * h7);
        for (int i2 = j8; i2 < num; i2 += 8) {
            int pos = start + i2;
            float ex = exbuf[(size_t)pos * 8 + h7];
            int e = eidx[pos];
            alpha_out[(size_t)e * 8 + h7] = ex * invh;
        }
    }
}

// ============================================================
extern "C" void kernel_launch(void* const* d_in, const int* in_sizes, int n_in,
                              void* d_out, int out_size, void* d_ws, size_t ws_size,
                              hipStream_t stream)
{
    const float* h        = (const float*)d_in[0];
    const int*   edge_idx = (const int*)  d_in[1];
    const float* edge_attr= (const float*)d_in[2];
    const float* w1       = (const float*)d_in[3];
    const float* b1       = (const float*)d_in[4];
    const float* w2       = (const float*)d_in[5];
    const float* b2       = (const float*)d_in[6];
    const float* ln_g     = (const float*)d_in[7];
    const float* ln_b     = (const float*)d_in[8];
    const float* Wl       = (const float*)d_in[9];
    const float* bl       = (const float*)d_in[10];
    const float* Wr       = (const float*)d_in[11];
    const float* br       = (const float*)d_in[12];
    const float* We       = (const float*)d_in[13];
    const float* att      = (const float*)d_in[14];
    const float* bias_out = (const float*)d_in[15];

    float* out   = (float*)d_out;                       // [N,128]
    float* alpha = out + (size_t)N_NODES * 128;         // [E,8] final alpha

    short8* w1p = (short8*)alpha;                       // packed weights live in
    short8* w2p = w1p + 128 * 64;                       // alpha region, consumed by
    short8* Wlp = w2p + 128 * 64;                       // node_ffn; alpha written last
    short8* Wrp = Wlp + 32 * 64;

    float*          v        = (float*)d_ws;                               // [N,128] f32
    unsigned short* xl_bf    = (unsigned short*)(v + (size_t)N_NODES*128); // [N,128] bf16
    unsigned short* xr_bf    = xl_bf + (size_t)N_NODES * 128;              // [N,128] bf16
    float*          exbuf    = (float*)(xr_bf + (size_t)N_NODES * 128);    // [E,8] f32 (ex)
    unsigned*       cnt      = (unsigned*)(exbuf + (size_t)E_EDGES * 8);   // [N]
    int*            rowstart = (int*)(cnt + N_NODES);                      // [N]
    unsigned short* rank     = (unsigned short*)(rowstart + N_NODES);      // [E]
    short8*         Wep      = (short8*)(rank + E_EDGES);                  // [512] 8 KB
    int*            eidx     = (int*)(Wep + 512);                          // [E]
    unsigned*       srcdst   = (unsigned*)(eidx + E_EDGES);                // [E]

    hipMemsetAsync(cnt, 0, (size_t)N_NODES * sizeof(unsigned), stream);

    repack_kernel<<<328, 64, 0, stream>>>(w1, w2, Wl, Wr, We,
                                          w1p, w2p, Wlp, Wrp, Wep);
    count_kernel<<<E_EDGES / 256, 256, 0, stream>>>(edge_idx, cnt, rank);
    node_ffn_mfma<<<N_NODES / 16, 256, 0, stream>>>(
        h, b1, b2, ln_g, ln_b, bl, br, w1p, w2p, Wlp, Wrp, v, xl_bf, xr_bf);
    scan_kernel<<<1, 1024, 0, stream>>>(cnt, rowstart);
    scatter_kernel<<<(E_EDGES + 255) / 256, 256, 0, stream>>>(
        edge_idx, rank, rowstart, eidx, srcdst);
    edge_logits_mfma<<<E_EDGES / 64, 256, 0, stream>>>(
        eidx, srcdst, edge_attr, Wep, att, xl_bf, xr_bf, exbuf);
    node_aggregate_kernel<<<(N_NODES + 3) / 4, 256, 0, stream>>>(
        eidx, rowstart, cnt, srcdst, exbuf, xl_bf, v, bias_out, ln_g, ln_b, alpha, out);
}

// Round 10
// 428.485 us; speedup vs baseline: 1.0573x; 1.0281x over previous
//
#include <hip/hip_runtime.h>
#include <math.h>

#define N_NODES 50000
#define E_EDGES 800000
#define D_DIM   128
#define H_HEADS 8
#define C_CH    16
#define HID_DIM 512
#define ED_DIM  32

typedef __attribute__((ext_vector_type(8))) short short8;
typedef __attribute__((ext_vector_type(4))) float f32x4;

__device__ __forceinline__ short f2bf(float f) {
    unsigned u = __float_as_uint(f);
    return (short)((u + 0x7FFFu + ((u >> 16) & 1u)) >> 16);  // RNE
}
__device__ __forceinline__ float bf2f(short s) {
    return __uint_as_float(((unsigned)(unsigned short)s) << 16);
}

// ============================================================
// Kernel SETUP: fused repack (82 blocks x 4 units) + count
// (3125 blocks). Saves one launch vs separate kernels.
// Repack: w1/w2/Wl/Wr/We (fp32 [K][N]) -> bf16 B-frag order.
// We gets the column permutation (tile t, col m = channel m*8+t)
// so the edge kernel's MFMA output is register-consumable.
// ============================================================
#define REPACK_BLOCKS 82
__global__ __launch_bounds__(256) void setup_kernel(
    const float* __restrict__ w1, const float* __restrict__ w2,
    const float* __restrict__ Wl, const float* __restrict__ Wr,
    const float* __restrict__ We,
    short8* __restrict__ w1p, short8* __restrict__ w2p,
    short8* __restrict__ Wlp, short8* __restrict__ Wrp,
    short8* __restrict__ Wep,
    const int* __restrict__ edge_index, unsigned* __restrict__ cnt,
    unsigned short* __restrict__ rank)
{
    int b = blockIdx.x;
    if (b < REPACK_BLOCKS) {
        int unit = b * 4 + (threadIdx.x >> 6);
        if (unit >= 328) return;
        const float* src; short8* dst; int Nw, nc, rel;
        bool perm = false;
        if (unit < 128)      { src = w1; dst = w1p; Nw = 512; nc = 4;  rel = unit; }
        else if (unit < 256) { src = w2; dst = w2p; Nw = 128; nc = 16; rel = unit - 128; }
        else if (unit < 288) { src = Wl; dst = Wlp; Nw = 128; nc = 4;  rel = unit - 256; }
        else if (unit < 320) { src = Wr; dst = Wrp; Nw = 128; nc = 4;  rel = unit - 288; }
        else                 { src = We; dst = Wep; Nw = 128; nc = 1;  rel = unit - 320; perm = true; }
        int t = rel / nc, c = rel % nc;
        int l = threadIdx.x & 63, quad = l >> 4, col = l & 15;
        short8 r;
        #pragma unroll
        for (int j = 0; j < 8; ++j) {
            if (perm)
                r[j] = f2bf(src[(size_t)(quad * 8 + j) * 128 + col * 8 + t]);
            else
                r[j] = f2bf(src[(size_t)(c * 32 + quad * 8 + j) * Nw + t * 16 + col]);
        }
        dst[(size_t)rel * 64 + l] = r;
    } else {
        int e = (b - REPACK_BLOCKS) * 256 + threadIdx.x;   // E % 256 == 0
        int dst = edge_index[E_EDGES + e];
        rank[e] = (unsigned short)atomicAdd(&cnt[dst], 1u);
    }
}

// ============================================================
// Kernel A: MFMA node pipeline. 16 nodes/block, 256 thr (4 waves).
// ============================================================
__global__ __launch_bounds__(256) void node_ffn_mfma(
    const float* __restrict__ h,
    const float* __restrict__ b1, const float* __restrict__ b2,
    const float* __restrict__ ln_g, const float* __restrict__ ln_b,
    const float* __restrict__ bl, const float* __restrict__ br,
    const short8* __restrict__ w1p, const short8* __restrict__ w2p,
    const short8* __restrict__ Wlp, const short8* __restrict__ Wrp,
    float* __restrict__ v_out,
    unsigned short* __restrict__ xl_bf_out, unsigned short* __restrict__ xr_bf_out)
{
    __shared__ short hid_bf[16 * 520];
    __shared__ float v_s[16 * 132];
    __shared__ short v_bf[16 * 136];

    const int tid = threadIdx.x;
    const int w = tid >> 6, lane = tid & 63;
    const int m = lane & 15, quad = lane >> 4;
    const int n0 = blockIdx.x * 16;

    short8 af[4];
    #pragma unroll
    for (int c = 0; c < 4; ++c) {
        const float* hp = h + (size_t)(n0 + m) * 128 + c * 32 + quad * 8;
        float4 p0 = ((const float4*)hp)[0];
        float4 p1 = ((const float4*)hp)[1];
        short8 a;
        a[0] = f2bf(p0.x); a[1] = f2bf(p0.y); a[2] = f2bf(p0.z); a[3] = f2bf(p0.w);
        a[4] = f2bf(p1.x); a[5] = f2bf(p1.y); a[6] = f2bf(p1.z); a[7] = f2bf(p1.w);
        af[c] = a;
    }

    {
        f32x4 acc[8];
        #pragma unroll
        for (int t = 0; t < 8; ++t) acc[t] = (f32x4){0.f, 0.f, 0.f, 0.f};
        #pragma unroll
        for (int t = 0; t < 8; ++t) {
            int tile = w * 8 + t;
            #pragma unroll
            for (int c = 0; c < 4; ++c) {
                short8 bf = w1p[(size_t)(tile * 4 + c) * 64 + lane];
                acc[t] = __builtin_amdgcn_mfma_f32_16x16x32_bf16(af[c], bf, acc[t], 0, 0, 0);
            }
        }
        #pragma unroll
        for (int t = 0; t < 8; ++t) {
            int col = (w * 8 + t) * 16 + m;
            float bias = b1[col];
            #pragma unroll
            for (int r = 0; r < 4; ++r) {
                int row = quad * 4 + r;
                hid_bf[row * 520 + col] = f2bf(fmaxf(acc[t][r] + bias, 0.f));
            }
        }
    }
    __syncthreads();

    {
        f32x4 acc2[2];
        acc2[0] = (f32x4){0.f, 0.f, 0.f, 0.f};
        acc2[1] = (f32x4){0.f, 0.f, 0.f, 0.f};
        #pragma unroll 4
        for (int c = 0; c < 16; ++c) {
            short8 a = *(const short8*)&hid_bf[m * 520 + c * 32 + quad * 8];
            #pragma unroll
            for (int t = 0; t < 2; ++t) {
                short8 bf = w2p[(size_t)((w * 2 + t) * 16 + c) * 64 + lane];
                acc2[t] = __builtin_amdgcn_mfma_f32_16x16x32_bf16(a, bf, acc2[t], 0, 0, 0);
            }
        }
        #pragma unroll
        for (int t = 0; t < 2; ++t) {
            int col = (w * 2 + t) * 16 + m;
            float bias = b2[col];
            #pragma unroll
            for (int r = 0; r < 4; ++r) {
                int row = quad * 4 + r;
                v_s[row * 132 + col] = acc2[t][r] + bias + h[(size_t)(n0 + row) * 128 + col];
            }
        }
    }
    __syncthreads();

    {
        float g0 = ln_g[lane], g1 = ln_g[lane + 64];
        float be0 = ln_b[lane], be1 = ln_b[lane + 64];
        #pragma unroll
        for (int p = 0; p < 4; ++p) {
            int nd = w * 4 + p;
            float x0 = v_s[nd * 132 + lane], x1 = v_s[nd * 132 + lane + 64];
            float s = x0 + x1, ss = x0 * x0 + x1 * x1;
            #pragma unroll
            for (int off = 1; off < 64; off <<= 1) {
                s  += __shfl_xor(s, off);
                ss += __shfl_xor(ss, off);
            }
            float mu = s * (1.f / 128.f);
            float var = ss * (1.f / 128.f) - mu * mu;
            float rs = rsqrtf(var + 1e-5f);
            float y0 = (x0 - mu) * rs * g0 + be0;
            float y1 = (x1 - mu) * rs * g1 + be1;
            v_out[(size_t)(n0 + nd) * 128 + lane]      = y0;
            v_out[(size_t)(n0 + nd) * 128 + lane + 64] = y1;
            v_bf[nd * 136 + lane]      = f2bf(y0);
            v_bf[nd * 136 + lane + 64] = f2bf(y1);
        }
    }
    __syncthreads();

    {
        short8 af3[4];
        #pragma unroll
        for (int c = 0; c < 4; ++c)
            af3[c] = *(const short8*)&v_bf[m * 136 + c * 32 + quad * 8];
        f32x4 accl[2], accr[2];
        #pragma unroll
        for (int t = 0; t < 2; ++t) {
            accl[t] = (f32x4){0.f, 0.f, 0.f, 0.f};
            accr[t] = (f32x4){0.f, 0.f, 0.f, 0.f};
        }
        #pragma unroll
        for (int t = 0; t < 2; ++t) {
            int tile = w * 2 + t;
            #pragma unroll
            for (int c = 0; c < 4; ++c) {
                accl[t] = __builtin_amdgcn_mfma_f32_16x16x32_bf16(
                    af3[c], Wlp[(size_t)(tile * 4 + c) * 64 + lane], accl[t], 0, 0, 0);
                accr[t] = __builtin_amdgcn_mfma_f32_16x16x32_bf16(
                    af3[c], Wrp[(size_t)(tile * 4 + c) * 64 + lane], accr[t], 0, 0, 0);
            }
        }
        #pragma unroll
        for (int t = 0; t < 2; ++t) {
            int col = (w * 2 + t) * 16 + m;
            float bld = bl[col], brd = br[col];
            #pragma unroll
            for (int r = 0; r < 4; ++r) {
                int row = quad * 4 + r;
                xl_bf_out[(size_t)(n0 + row) * 128 + col] = (unsigned short)f2bf(accl[t][r] + bld);
                xr_bf_out[(size_t)(n0 + row) * 128 + col] = (unsigned short)f2bf(accr[t][r] + brd);
            }
        }
    }
}

// ============================================================
// Kernel S1: exclusive scan, single pass.
// ============================================================
__global__ __launch_bounds__(1024) void scan_kernel(
    const unsigned* __restrict__ cnt, int* __restrict__ rowstart)
{
    __shared__ int wsum[16];
    const int t = threadIdx.x, wv = t >> 6, lane = t & 63;
    const int base4 = t * 13;
    int4 v[13];
    int lsum = 0;
    #pragma unroll
    for (int k = 0; k < 13; ++k) {
        int i4 = base4 + k;
        int4 x = make_int4(0, 0, 0, 0);
        if (i4 < N_NODES / 4) x = ((const int4*)cnt)[i4];
        v[k] = x;
        lsum += x.x + x.y + x.z + x.w;
    }
    int s = lsum;
    #pragma unroll
    for (int off = 1; off < 64; off <<= 1) {
        int nb = __shfl_up(s, off);
        if (lane >= off) s += nb;
    }
    if (lane == 63) wsum[wv] = s;
    __syncthreads();
    int woff = 0;
    for (int k = 0; k < wv; ++k) woff += wsum[k];
    int run = woff + s - lsum;          // exclusive prefix for this thread
    #pragma unroll
    for (int k = 0; k < 13; ++k) {
        int i4 = base4 + k;
        if (i4 < N_NODES / 4) {
            int4 r;
            r.x = run; run += v[k].x;
            r.y = run; run += v[k].y;
            r.z = run; run += v[k].z;
            r.w = run; run += v[k].w;
            ((int4*)rowstart)[i4] = r;
        }
    }
}

// ============================================================
// Kernel S2: scatter edge ids + packed (src,dst) into CSR order
// ============================================================
__global__ __launch_bounds__(256) void scatter_kernel(
    const int* __restrict__ edge_index, const unsigned short* __restrict__ rank,
    const int* __restrict__ rowstart, int* __restrict__ eidx,
    unsigned* __restrict__ srcdst)
{
    int e = blockIdx.x * 256 + threadIdx.x;
    if (e >= E_EDGES) return;
    int src = edge_index[e];
    int dst = edge_index[E_EDGES + e];
    int pos = rowstart[dst] + (int)rank[e];
    eidx[pos] = e;
    srcdst[pos] = (unsigned)src | ((unsigned)dst << 16);   // N < 65536
}

// ============================================================
// Kernel B: edge ex, CSR order. TWO 16-edge tiles per wave:
// 2 independent eidx->ea chains + 2 MFMAs + 16 gathers in
// flight per wave (double memory-level parallelism against the
// ~16-waves/CU register cap). Register-resident xe via permuted
// Wep; uint4 meta prefetch; LDS = We only; one barrier.
// Block = 128 edges, grid = E/128.
// ============================================================
__global__ __launch_bounds__(256) void edge_logits_mfma(
    const int* __restrict__ eidx, const unsigned* __restrict__ srcdst,
    const float* __restrict__ edge_attr,
    const short8* __restrict__ Wep, const float* __restrict__ att,
    const unsigned short* __restrict__ xl_bf, const unsigned short* __restrict__ xr_bf,
    float* __restrict__ exbuf)
{
    __shared__ short8 We_f[512];       // 8 KB, permuted B-frag order
    const int tid = threadIdx.x;
    const int w = tid >> 6, lane = tid & 63;
    const int m = lane & 15, quad = lane >> 4;
    const int p0b = blockIdx.x * 128;  // CSR position base
    const int base = p0b + w * 32;     // this wave's 32 edges

    We_f[tid]       = Wep[tid];
    We_f[tid + 256] = Wep[tid + 256];

    // meta prefetch: 2 x uint4 (this lane's 8 edges' src|dst)
    uint4 sd4a = *((const uint4*)&srcdst[base + quad * 4]);
    uint4 sd4b = *((const uint4*)&srcdst[base + 16 + quad * 4]);

    // two independent eidx -> edge_attr gather chains
    int em0 = eidx[base + m];
    int em1 = eidx[base + 16 + m];
    const float* eap0 = edge_attr + (size_t)em0 * 32 + quad * 8;
    const float* eap1 = edge_attr + (size_t)em1 * 32 + quad * 8;
    float4 q00 = ((const float4*)eap0)[0];
    float4 q01 = ((const float4*)eap0)[1];
    float4 q10 = ((const float4*)eap1)[0];
    float4 q11 = ((const float4*)eap1)[1];
    short8 a0, a1;
    a0[0] = f2bf(q00.x); a0[1] = f2bf(q00.y); a0[2] = f2bf(q00.z); a0[3] = f2bf(q00.w);
    a0[4] = f2bf(q01.x); a0[5] = f2bf(q01.y); a0[6] = f2bf(q01.z); a0[7] = f2bf(q01.w);
    a1[0] = f2bf(q10.x); a1[1] = f2bf(q10.y); a1[2] = f2bf(q10.z); a1[3] = f2bf(q10.w);
    a1[4] = f2bf(q11.x); a1[5] = f2bf(q11.y); a1[6] = f2bf(q11.z); a1[7] = f2bf(q11.w);

    __syncthreads();   // We_f ready (only barrier)

    // xe for both tiles, register-resident (permuted layout)
    f32x4 acc0[8], acc1[8];
    #pragma unroll
    for (int t = 0; t < 8; ++t) {
        acc0[t] = (f32x4){0.f, 0.f, 0.f, 0.f};
        acc1[t] = (f32x4){0.f, 0.f, 0.f, 0.f};
    }
    #pragma unroll
    for (int t = 0; t < 8; ++t) {
        short8 bf = We_f[t * 64 + lane];
        acc0[t] = __builtin_amdgcn_mfma_f32_16x16x32_bf16(a0, bf, acc0[t], 0, 0, 0);
        acc1[t] = __builtin_amdgcn_mfma_f32_16x16x32_bf16(a1, bf, acc1[t], 0, 0, 0);
    }

    const int d0 = m * 8;
    float4 at0 = ((const float4*)(att + d0))[0];
    float4 at1 = ((const float4*)(att + d0))[1];
    float atv[8] = { at0.x, at0.y, at0.z, at0.w, at1.x, at1.y, at1.z, at1.w };
    const unsigned sdsa[4] = { sd4a.x, sd4a.y, sd4a.z, sd4a.w };
    const unsigned sdsb[4] = { sd4b.x, sd4b.y, sd4b.z, sd4b.w };

    // per-edge phase: 8 edges per lane-group, 16 gathers in flight
    #pragma unroll
    for (int r = 0; r < 4; ++r) {
        unsigned sa = sdsa[r], sb = sdsb[r];
        short8 xl0 = *(const short8*)&xl_bf[(size_t)(sa & 0xffffu) * 128 + d0];
        short8 xr0 = *(const short8*)&xr_bf[(size_t)(sa >> 16) * 128 + d0];
        short8 xl1 = *(const short8*)&xl_bf[(size_t)(sb & 0xffffu) * 128 + d0];
        short8 xr1 = *(const short8*)&xr_bf[(size_t)(sb >> 16) * 128 + d0];

        float pq0 = 0.f, pq1 = 0.f;
        #pragma unroll
        for (int t = 0; t < 8; ++t) {
            float x0 = bf2f(xl0[t]) + bf2f(xr0[t]) + acc0[t][r];
            float x1 = bf2f(xl1[t]) + bf2f(xr1[t]) + acc1[t][r];
            x0 = fmaxf(x0, 0.2f * x0);           // leakyrelu(x, 0.2)
            x1 = fmaxf(x1, 0.2f * x1);
            pq0 += x0 * atv[t];
            pq1 += x1 * atv[t];
        }
        pq0 += __shfl_xor(pq0, 1);
        pq1 += __shfl_xor(pq1, 1);
        if ((m & 1) == 0) {
            int el0 = base + quad * 4 + r;
            int el1 = el0 + 16;
            exbuf[(size_t)el0 * 8 + (m >> 1)] = __expf(pq0);
            exbuf[(size_t)el1 * 8 + (m >> 1)] = __expf(pq1);
        }
    }
}

// ============================================================
// Kernel C: per-node aggregation, ONE pass with 8 edges in
// flight: U = sum ex*xl, den = sum ex; out = LN(U/den+bias+v);
// alpha sweep writes alpha[e][h] = ex*inv.
// ============================================================
__global__ __launch_bounds__(256) void node_aggregate_kernel(
    const int* __restrict__ eidx, const int* __restrict__ rowstart,
    const unsigned* __restrict__ cnt, const unsigned* __restrict__ srcdst,
    const float* __restrict__ exbuf,
    const unsigned short* __restrict__ xl_bf, const float* __restrict__ v,
    const float* __restrict__ bias_out,
    const float* __restrict__ ln_g, const float* __restrict__ ln_b,
    float* __restrict__ alpha_out, float* __restrict__ out)
{
    const int wv = threadIdx.x >> 6, lane = threadIdx.x & 63;
    const int n = blockIdx.x * 4 + wv;
    if (n >= N_NODES) return;
    const int start = rowstart[n];
    const int num = (int)cnt[n];

    const int g = lane >> 4, s = lane & 15;
    const int h3 = s >> 1;
    float acc[8] = {0.f, 0.f, 0.f, 0.f, 0.f, 0.f, 0.f, 0.f};
    float den = 0.f;

    int i = 0;
    for (; i + 8 <= num; i += 8) {
        int pos0 = start + i + g;
        int pos1 = pos0 + 4;
        unsigned sda = srcdst[pos0];
        unsigned sdb = srcdst[pos1];
        float exa = exbuf[(size_t)pos0 * 8 + h3];
        float exb = exbuf[(size_t)pos1 * 8 + h3];
        short8 qa = *(const short8*)&xl_bf[(size_t)(sda & 0xffffu) * 128 + s * 8];
        short8 qb = *(const short8*)&xl_bf[(size_t)(sdb & 0xffffu) * 128 + s * 8];
        if ((s & 1) == 0) den += exa + exb;
        #pragma unroll
        for (int k = 0; k < 8; ++k) {
            acc[k] += bf2f(qa[k]) * exa;
            acc[k] += bf2f(qb[k]) * exb;
        }
    }
    for (; i < num; i += 4) {
        int ii = i + g;
        if (ii < num) {
            int pos = start + ii;
            int src = (int)(srcdst[pos] & 0xffffu);
            float ex = exbuf[(size_t)pos * 8 + h3];
            if ((s & 1) == 0) den += ex;
            short8 q = *(const short8*)&xl_bf[(size_t)src * 128 + s * 8];
            #pragma unroll
            for (int k = 0; k < 8; ++k) acc[k] += bf2f(q[k]) * ex;
        }
    }
    #pragma unroll
    for (int k = 0; k < 8; ++k) {
        acc[k] += __shfl_xor(acc[k], 16);
        acc[k] += __shfl_xor(acc[k], 32);
    }
    den += __shfl_xor(den, 16);
    den += __shfl_xor(den, 32);
    float den_h = __shfl(den, 2 * h3);
    float inv = (num > 0) ? (1.f / den_h) : 0.f;

    const float* vp = v + (size_t)n * 128 + s * 8;
    float4 v0 = ((const float4*)vp)[0], v1 = ((const float4*)vp)[1];
    float4 b0 = ((const float4*)(bias_out + s * 8))[0];
    float4 b1 = ((const float4*)(bias_out + s * 8))[1];
    float x[8];
    x[0] = acc[0] * inv + b0.x + v0.x; x[1] = acc[1] * inv + b0.y + v0.y;
    x[2] = acc[2] * inv + b0.z + v0.z; x[3] = acc[3] * inv + b0.w + v0.w;
    x[4] = acc[4] * inv + b1.x + v1.x; x[5] = acc[5] * inv + b1.y + v1.y;
    x[6] = acc[6] * inv + b1.z + v1.z; x[7] = acc[7] * inv + b1.w + v1.w;
    float sm = 0.f, ssm = 0.f;
    #pragma unroll
    for (int k = 0; k < 8; ++k) { sm += x[k]; ssm += x[k] * x[k]; }
    #pragma unroll
    for (int off = 1; off < 16; off <<= 1) {
        sm  += __shfl_xor(sm, off);
        ssm += __shfl_xor(ssm, off);
    }
    float mu = sm * (1.f / 128.f);
    float var = ssm * (1.f / 128.f) - mu * mu;
    float rs = rsqrtf(var + 1e-5f);
    if (g == 0) {
        float4 g0 = ((const float4*)(ln_g + s * 8))[0];
        float4 g1 = ((const float4*)(ln_g + s * 8))[1];
        float4 be0 = ((const float4*)(ln_b + s * 8))[0];
        float4 be1 = ((const float4*)(ln_b + s * 8))[1];
        float4 o0, o1;
        o0.x = (x[0] - mu) * rs * g0.x + be0.x;
        o0.y = (x[1] - mu) * rs * g0.y + be0.y;
        o0.z = (x[2] - mu) * rs * g0.z + be0.z;
        o0.w = (x[3] - mu) * rs * g0.w + be0.w;
        o1.x = (x[4] - mu) * rs * g1.x + be1.x;
        o1.y = (x[5] - mu) * rs * g1.y + be1.y;
        o1.z = (x[6] - mu) * rs * g1.z + be1.z;
        o1.w = (x[7] - mu) * rs * g1.w + be1.w;
        float4* op = (float4*)(out + (size_t)n * 128 + s * 8);
        op[0] = o0; op[1] = o1;
    }

    if (num > 0) {
        const int h7 = lane & 7, j8 = lane >> 3;
        float invh = __shfl(inv, 2 * h7);
        for (int i2 = j8; i2 < num; i2 += 8) {
            int pos = start + i2;
            float ex = exbuf[(size_t)pos * 8 + h7];
            int e = eidx[pos];
            alpha_out[(size_t)e * 8 + h7] = ex * invh;
        }
    }
}

// ============================================================
extern "C" void kernel_launch(void* const* d_in, const int* in_sizes, int n_in,
                              void* d_out, int out_size, void* d_ws, size_t ws_size,
                              hipStream_t stream)
{
    const float* h        = (const float*)d_in[0];
    const int*   edge_idx = (const int*)  d_in[1];
    const float* edge_attr= (const float*)d_in[2];
    const float* w1       = (const float*)d_in[3];
    const float* b1       = (const float*)d_in[4];
    const float* w2       = (const float*)d_in[5];
    const float* b2       = (const float*)d_in[6];
    const float* ln_g     = (const float*)d_in[7];
    const float* ln_b     = (const float*)d_in[8];
    const float* Wl       = (const float*)d_in[9];
    const float* bl       = (const float*)d_in[10];
    const float* Wr       = (const float*)d_in[11];
    const float* br       = (const float*)d_in[12];
    const float* We       = (const float*)d_in[13];
    const float* att      = (const float*)d_in[14];
    const float* bias_out = (const float*)d_in[15];

    float* out   = (float*)d_out;                       // [N,128]
    float* alpha = out + (size_t)N_NODES * 128;         // [E,8] final alpha

    short8* w1p = (short8*)alpha;                       // packed weights live in
    short8* w2p = w1p + 128 * 64;                       // alpha region, consumed by
    short8* Wlp = w2p + 128 * 64;                       // node_ffn; alpha written last
    short8* Wrp = Wlp + 32 * 64;

    float*          v        = (float*)d_ws;                               // [N,128] f32
    unsigned short* xl_bf    = (unsigned short*)(v + (size_t)N_NODES*128); // [N,128] bf16
    unsigned short* xr_bf    = xl_bf + (size_t)N_NODES * 128;              // [N,128] bf16
    float*          exbuf    = (float*)(xr_bf + (size_t)N_NODES * 128);    // [E,8] f32 (ex)
    unsigned*       cnt      = (unsigned*)(exbuf + (size_t)E_EDGES * 8);   // [N]
    int*            rowstart = (int*)(cnt + N_NODES);                      // [N]
    unsigned short* rank     = (unsigned short*)(rowstart + N_NODES);      // [E]
    short8*         Wep      = (short8*)(rank + E_EDGES);                  // [512] 8 KB
    int*            eidx     = (int*)(Wep + 512);                          // [E]
    unsigned*       srcdst   = (unsigned*)(eidx + E_EDGES);                // [E]

    hipMemsetAsync(cnt, 0, (size_t)N_NODES * sizeof(unsigned), stream);

    setup_kernel<<<REPACK_BLOCKS + E_EDGES / 256, 256, 0, stream>>>(
        w1, w2, Wl, Wr, We, w1p, w2p, Wlp, Wrp, Wep, edge_idx, cnt, rank);
    node_ffn_mfma<<<N_NODES / 16, 256, 0, stream>>>(
        h, b1, b2, ln_g, ln_b, bl, br, w1p, w2p, Wlp, Wrp, v, xl_bf, xr_bf);
    scan_kernel<<<1, 1024, 0, stream>>>(cnt, rowstart);
    scatter_kernel<<<(E_EDGES + 255) / 256, 256, 0, stream>>>(
        edge_idx, rank, rowstart, eidx, srcdst);
    edge_logits_mfma<<<E_EDGES / 128, 256, 0, stream>>>(
        eidx, srcdst, edge_attr, Wep, att, xl_bf, xr_bf, exbuf);
    node_aggregate_kernel<<<(N_NODES + 3) / 4, 256, 0, stream>>>(
        eidx, rowstart, cnt, srcdst, exbuf, xl_bf, v, bias_out, ln_g, ln_b, alpha, out);
}